// Round 7
// baseline (165.252 us; speedup 1.0000x reference)
//
#include <hip/hip_runtime.h>
#include <stdint.h>
#include <stddef.h>

// GraphCoarsenLayer: out = x@W_self + mean(x[nbr[:, :16]])@W_neigh
//                        + mean(x[nbr[:,16:]])@W_coarsen + (b_self+b_neigh+b_coarsen)
// R7: COMMUTED structure. mean(x[S])@W == mean((x@W)[S]) (linearity), so:
//   1) Y = x @ [Wself|Wneigh|Wcoar]  (M=50176, N'=768, K=256) — one GEMM, A read
//      directly from f32 x (rows are K-contiguous), self-part+bias written f32 to
//      out, neigh/coarsen parts written fp8-e4m3 to Y8n/Y8c tables.
//   2) gather: out[i] += (1/16)(sum_{j<16} Y8n[nbr] + sum_{j>=16} Y8c[nbr]).
// Kills the convert kernel, the Ax/agg intermediates, and triples the GEMM grid
// (2352 blocks) to fix the measured occupancy starvation.

#define NN   50000
#define NPAD 50176          // multiple of 128; 392 mt-tiles
#define CDIM 256            // K
#define NW   768            // GEMM output width

typedef __bf16 bf16x8 __attribute__((ext_vector_type(8)));
typedef float  f32x4  __attribute__((ext_vector_type(4)));
typedef float  f32x2  __attribute__((ext_vector_type(2)));

static __device__ __forceinline__ unsigned short f2b(float f) {
    unsigned u = __builtin_bit_cast(unsigned, f);
    u += 0x7fffu + ((u >> 16) & 1u);          // round-to-nearest-even
    return (unsigned short)(u >> 16);
}

// ---------------- kernel 1: pack B = [Wself|Wneigh|Wcoar] K-chunked + bias ------
// Wb layout: [(g*768 + n)*8 + j], k = g*8 + j  (g = 0..31)
__global__ void k_prep_w(const float* __restrict__ Wself, const float* __restrict__ bself,
                         const float* __restrict__ Wneigh, const float* __restrict__ bneigh,
                         const float* __restrict__ Wcoar, const float* __restrict__ bcoar,
                         unsigned short* __restrict__ Wb, float* __restrict__ bias) {
    int k = blockIdx.x;      // 0..255 (K row)
    int n = threadIdx.x;     // 0..767 (concat output col)
    const float* W = (n < 256) ? Wself : (n < 512) ? Wneigh : Wcoar;
    int nl = n & 255;
    float v = W[(size_t)k * 256 + nl];
    int g = k >> 3, j = k & 7;
    Wb[((size_t)g * NW + n) * 8 + j] = f2b(v);
    if (k == 0 && n < 256) bias[n] = bself[n] + bneigh[n] + bcoar[n];
}

// ---------------- kernel 2: GEMM Y = x @ Wb ------------------------------------
// Tile 128x128 of Y, 4 waves (2x2, wave 64x64), K=256 in 8 steps, depth-3 register
// pipeline, LDS-free/barrier-free. A loaded f32 (32B/lane) + in-reg bf16 cast.
// nt<2 -> out (f32 + bias); nt 2..5 -> fp8 tables.
__global__ __launch_bounds__(256, 2) void k_gemm(const float* __restrict__ x,
                                                 const unsigned short* __restrict__ Wb,
                                                 const float* __restrict__ bias,
                                                 float* __restrict__ out,
                                                 unsigned char* __restrict__ Y8n,
                                                 unsigned char* __restrict__ Y8c) {
    const int tid  = threadIdx.x;
    const int wid  = tid >> 6;
    const int lane = tid & 63;
    const int l15 = lane & 15, l4 = lane >> 4;

    // XCD swizzle: 48 consecutive bids = 8 mt x 6 nt; same-mt blocks share bid%8.
    const int bid = blockIdx.x;                // 2352 = 49 * 48
    const int g48 = bid / 48, r48 = bid - g48 * 48;
    const int mt = g48 * 8 + (r48 & 7);        // 0..391
    const int nt = r48 >> 3;                   // 0..5
    const int row0 = mt * 128;
    const int n0   = nt * 128;
    const int wm = (wid >> 1) * 64, wn = (wid & 1) * 64;

    // A row pointers (clamped: rows >= NN read row NN-1; those outputs are dropped)
    const float* ap[4];
#pragma unroll
    for (int mi = 0; mi < 4; ++mi) {
        int r = row0 + wm + mi * 16 + l15;
        if (r > NN - 1) r = NN - 1;
        ap[mi] = x + (size_t)r * CDIM + l4 * 8;
    }

    f32x4  acc[4][4] = {};
    f32x4  Af[3][4][2];                        // f32 staging (depth-3, static idx)
    bf16x8 Bs[3][4];

    auto loadA = [&](int s, int t) {
#pragma unroll
        for (int mi = 0; mi < 4; ++mi) {
            Af[s][mi][0] = *(const f32x4*)(ap[mi] + t * 32);
            Af[s][mi][1] = *(const f32x4*)(ap[mi] + t * 32 + 4);
        }
    };
    auto loadB = [&](int s, int t) {
        const int g = t * 4 + l4;              // K-chunk 0..31
#pragma unroll
        for (int ni = 0; ni < 4; ++ni)
            Bs[s][ni] = *(const bf16x8*)(Wb + ((size_t)g * NW + n0 + wn + ni * 16 + l15) * 8);
    };
    auto step = [&](int s) {
#pragma unroll
        for (int mi = 0; mi < 4; ++mi) {
            bf16x8 a;
#pragma unroll
            for (int j = 0; j < 4; ++j) {
                a[j]     = (__bf16)Af[s][mi][0][j];
                a[4 + j] = (__bf16)Af[s][mi][1][j];
            }
#pragma unroll
            for (int ni = 0; ni < 4; ++ni)
                acc[mi][ni] = __builtin_amdgcn_mfma_f32_16x16x32_bf16(
                    a, Bs[s][ni], acc[mi][ni], 0, 0, 0);
        }
    };

    loadA(0, 0); loadB(0, 0);
    loadA(1, 1); loadB(1, 1);
#pragma unroll
    for (int t = 0; t < 8; ++t) {
        if (t + 2 < 8) { loadA((t + 2) % 3, t + 2); loadB((t + 2) % 3, t + 2); }
        step(t % 3);
    }

    // epilogue: D layout col=lane&15, row=(lane>>4)*4+r
    if (nt < 2) {                              // self part -> out (f32, +bias)
#pragma unroll
        for (int mi = 0; mi < 4; ++mi) {
            const int row = row0 + wm + mi * 16 + l4 * 4;
#pragma unroll
            for (int ni = 0; ni < 4; ++ni) {
                const int col = n0 + wn + ni * 16 + l15;
                const float bb = bias[col];
                f32x4 v = acc[mi][ni];
#pragma unroll
                for (int r = 0; r < 4; ++r) {
                    const int rr = row + r;
                    if (rr < NN) out[(size_t)rr * 256 + col] = v[r] + bb;
                }
            }
        }
    } else {                                   // neigh/coarsen -> fp8 tables
        unsigned char* G = (nt < 4) ? Y8n : Y8c;
        const int coff = (nt < 4) ? 256 : 512;
#pragma unroll
        for (int mi = 0; mi < 4; ++mi) {
            const int row = row0 + wm + mi * 16 + l4 * 4;
#pragma unroll
            for (int ni = 0; ni < 4; ++ni) {
                const int col = n0 - coff + wn + ni * 16 + l15;
                f32x4 v = acc[mi][ni];
                unsigned w0 = __builtin_amdgcn_cvt_pk_fp8_f32(v[0], v[1], 0, false);
                unsigned w1 = __builtin_amdgcn_cvt_pk_fp8_f32(v[2], v[3], 0, false);
                if (row + 0 < NN) G[(size_t)(row + 0) * 256 + col] = (unsigned char)(w0 & 0xff);
                if (row + 1 < NN) G[(size_t)(row + 1) * 256 + col] = (unsigned char)((w0 >> 8) & 0xff);
                if (row + 2 < NN) G[(size_t)(row + 2) * 256 + col] = (unsigned char)(w1 & 0xff);
                if (row + 3 < NN) G[(size_t)(row + 3) * 256 + col] = (unsigned char)((w1 >> 8) & 0xff);
            }
        }
    }
}

// ---------------- kernel 3: gather-mean + accumulate into out ------------------
// Wave per node; lane owns 4 cols. j<16 reads Y8n row, j>=16 reads Y8c row.
__global__ __launch_bounds__(512) void k_gather_out(const int* __restrict__ nbr,
                                                    const unsigned char* __restrict__ Y8n,
                                                    const unsigned char* __restrict__ Y8c,
                                                    float* __restrict__ out) {
    const int wid  = threadIdx.x >> 6;
    const int lane = threadIdx.x & 63;
    const int i = blockIdx.x * 8 + wid;        // NN = 6250*8 exactly
    const int* nb = nbr + (size_t)i * 32;
    float s0 = 0, s1 = 0, s2 = 0, s3 = 0;
#pragma unroll
    for (int j = 0; j < 32; ++j) {
        const int idx = nb[j];
        const unsigned char* base = (j < 16) ? Y8n : Y8c;
        unsigned d = *(const unsigned*)(base + (size_t)idx * 256 + lane * 4);
        f32x2 lo = __builtin_amdgcn_cvt_pk_f32_fp8(d, false);
        f32x2 hi = __builtin_amdgcn_cvt_pk_f32_fp8(d, true);
        s0 += lo[0]; s1 += lo[1]; s2 += hi[0]; s3 += hi[1];
    }
    const float rc = 1.0f / 16.0f;
    f32x4* po = (f32x4*)(out + (size_t)i * 256 + lane * 4);
    f32x4 o = *po;
    o[0] += s0 * rc; o[1] += s1 * rc; o[2] += s2 * rc; o[3] += s3 * rc;
    *po = o;
}

// ---------------- launch -------------------------------------------------------
extern "C" void kernel_launch(void* const* d_in, const int* in_sizes, int n_in,
                              void* d_out, int out_size, void* d_ws, size_t ws_size,
                              hipStream_t stream) {
    const float* x      = (const float*)d_in[0];
    const float* Wself  = (const float*)d_in[1];
    const float* bself  = (const float*)d_in[2];
    const float* Wneigh = (const float*)d_in[3];
    const float* bneigh = (const float*)d_in[4];
    const float* Wcoar  = (const float*)d_in[5];
    const float* bcoar  = (const float*)d_in[6];
    const int*   nbr    = (const int*)d_in[7];
    float* out = (float*)d_out;

    // workspace: Wb (384 KB) | bias (1 KB) | Y8n (12.85 MB) | Y8c (12.85 MB) ~= 26 MB
    unsigned short* Wb   = (unsigned short*)d_ws;
    float*          bias = (float*)(Wb + (size_t)32 * NW * 8);
    unsigned char*  Y8n  = (unsigned char*)(bias + 256);
    unsigned char*  Y8c  = Y8n + (size_t)NPAD * 256;

    k_prep_w<<<256, 768, 0, stream>>>(Wself, bself, Wneigh, bneigh, Wcoar, bcoar, Wb, bias);
    k_gemm<<<2352, 256, 0, stream>>>(x, Wb, bias, out, Y8n, Y8c);
    k_gather_out<<<NN / 8, 512, 0, stream>>>(nbr, Y8n, Y8c, out);
}

// Round 8
// 105.356 us; speedup vs baseline: 1.5685x; 1.5685x over previous
//
#include <hip/hip_runtime.h>
#include <stdint.h>
#include <stddef.h>

// GraphCoarsenLayer: out = x@W_self + mean(x[nbr[:, :16]])@W_neigh
//                        + mean(x[nbr[:,16:]])@W_coarsen + (b_self+b_neigh+b_coarsen)
// R8: non-commuted pipeline (R5/R6 producers) + GEMM rebuilt: BM=128 x BN=256 (A read
// ONCE), BK=32, 8 waves, 3-buffer global_load_lds pipeline with counted vmcnt(3)
// (hardware queue keeps a full tile in flight across each barrier — the compiler
// provably sank register-level prefetches in R6/R7, VGPR_Count=64 evidence).

#define NN   50000
#define NPAD 50176          // multiple of 128; 392 row-tiles of 128
#define ODIM 256
#define NTK  24             // 768 / 32 K-steps

typedef __bf16 bf16x8 __attribute__((ext_vector_type(8)));
typedef float  f32x4  __attribute__((ext_vector_type(4)));
typedef float  f32x2  __attribute__((ext_vector_type(2)));
typedef unsigned short u16x8 __attribute__((ext_vector_type(8)));
typedef unsigned short u16x4 __attribute__((ext_vector_type(4)));

static __device__ __forceinline__ unsigned short f2b(float f) {
    unsigned u = __builtin_bit_cast(unsigned, f);
    u += 0x7fffu + ((u >> 16) & 1u);          // round-to-nearest-even
    return (unsigned short)(u >> 16);
}

// ---------------- kernel 1: pack weights (K-chunked) + bias sum ----------------
// Wb layout: [g*256 + n]*8 + j  where k = g*8 + j  (g = 0..95)
__global__ void k_prep_w(const float* __restrict__ Wself, const float* __restrict__ bself,
                         const float* __restrict__ Wneigh, const float* __restrict__ bneigh,
                         const float* __restrict__ Wcoar, const float* __restrict__ bcoar,
                         unsigned short* __restrict__ Wb, float* __restrict__ bias) {
    int k = blockIdx.x;      // 0..767
    int n = threadIdx.x;     // 0..255
    const float* W = (k < 256) ? Wself : (k < 512) ? Wneigh : Wcoar;
    int kl = k & 255;
    float v = W[(size_t)kl * ODIM + n];
    int g = k >> 3;
    int j = k & 7;
    Wb[((size_t)g * ODIM + n) * 8 + j] = f2b(v);
    if (k == 0) bias[n] = bself[n] + bneigh[n] + bcoar[n];
}

// ---------------- kernel 2: x (f32) -> Ax chunked g<32 (bf16) + X8 fp8 ---------
__global__ void k_convert_x(const float* __restrict__ x, unsigned short* __restrict__ Ax,
                            unsigned char* __restrict__ X8) {
    int p = blockIdx.x * 256 + threadIdx.x;    // one 8-element chunk per thread
    if (p >= NN * 32) return;
    int i  = p >> 5;
    int c8 = p & 31;
    const f32x4* src = (const f32x4*)(x + (size_t)i * 256 + c8 * 8);
    f32x4 v0 = src[0], v1 = src[1];
    u16x8 o;
    o[0] = f2b(v0[0]); o[1] = f2b(v0[1]); o[2] = f2b(v0[2]); o[3] = f2b(v0[3]);
    o[4] = f2b(v1[0]); o[5] = f2b(v1[1]); o[6] = f2b(v1[2]); o[7] = f2b(v1[3]);
    *(u16x8*)(Ax + ((size_t)c8 * NPAD + i) * 8) = o;      // chunked layout
    unsigned d0 = __builtin_amdgcn_cvt_pk_fp8_f32(v0[0], v0[1], 0, false);
    d0 = (unsigned)__builtin_amdgcn_cvt_pk_fp8_f32(v0[2], v0[3], d0, true);
    unsigned d1 = __builtin_amdgcn_cvt_pk_fp8_f32(v1[0], v1[1], 0, false);
    d1 = (unsigned)__builtin_amdgcn_cvt_pk_fp8_f32(v1[2], v1[3], d1, true);
    uint2 o8; o8.x = d0; o8.y = d1;
    *(uint2*)(X8 + (size_t)i * 256 + c8 * 8) = o8;
}

// ---------------- kernel 3: gather-mean -> Ax chunks g 32..95 ------------------
// 8 waves = 8 nodes per block (wave-per-node keeps full TLP); LDS transpose so
// HBM writes are 128B-contiguous.
__global__ __launch_bounds__(512) void k_gather(const int* __restrict__ nbr,
                                                const unsigned char* __restrict__ X8,
                                                unsigned short* __restrict__ Ax) {
    __shared__ unsigned short aggl[8][512];
    const int wid  = threadIdx.x >> 6;
    const int lane = threadIdx.x & 63;
    const int i = blockIdx.x * 8 + wid;        // NN = 6250*8 exactly
    const int* nb = nbr + (size_t)i * 32;
    float s0 = 0, s1 = 0, s2 = 0, s3 = 0, u0 = 0, u1 = 0, u2 = 0, u3 = 0;
#pragma unroll
    for (int j = 0; j < 32; ++j) {
        int idx = nb[j];
        unsigned d = *(const unsigned*)(X8 + (size_t)idx * 256 + lane * 4);
        f32x2 lo = __builtin_amdgcn_cvt_pk_f32_fp8(d, false);
        f32x2 hi = __builtin_amdgcn_cvt_pk_f32_fp8(d, true);
        if (j < 16) { s0 += lo[0]; s1 += lo[1]; s2 += hi[0]; s3 += hi[1]; }
        else        { u0 += lo[0]; u1 += lo[1]; u2 += hi[0]; u3 += hi[1]; }
    }
    const float rc = 1.0f / 16.0f;
    u16x4 os = { f2b(s0 * rc), f2b(s1 * rc), f2b(s2 * rc), f2b(s3 * rc) };
    u16x4 ou = { f2b(u0 * rc), f2b(u1 * rc), f2b(u2 * rc), f2b(u3 * rc) };
    *(u16x4*)&aggl[wid][lane * 4]       = os;   // cols 0..255   (k 256..511)
    *(u16x4*)&aggl[wid][256 + lane * 4] = ou;   // cols 256..511 (k 512..767)
    __syncthreads();
    const int tau = threadIdx.x;
    const int gl = tau >> 3, r = tau & 7;       // 64 chunks x 8 rows
    u16x8 v = *(const u16x8*)&aggl[r][gl * 8];
    *(u16x8*)(Ax + ((size_t)(32 + gl) * NPAD + blockIdx.x * 8 + r) * 8) = v;
}

// ---------------- kernel 4: GEMM  out[N,256] = A[N,768] @ Wb + bias ------------
// BM=128, BN=256 (full width -> A read once), BK=32. 512 threads = 8 waves (2x4),
// wave tile 64x64. 3-buffer LDS (3 x 24KB), counted vmcnt(3): one tile always in
// flight across the barrier; ONE barrier per K-step.
__global__ __launch_bounds__(512, 4) void k_gemm(const unsigned short* __restrict__ Ax,
                                                 const unsigned short* __restrict__ Wb,
                                                 const float* __restrict__ bias,
                                                 float* __restrict__ out) {
    __shared__ __align__(16) unsigned short lds[3][12288];  // [buf][A 4096 | B 8192] u16
    const int tid  = threadIdx.x;
    const int wid  = tid >> 6;
    const int lane = tid & 63;
    const int l15 = lane & 15, l4 = lane >> 4;
    const int row0 = blockIdx.x * 128;
    const int wr = wid >> 2, wc = wid & 3;      // 2x4 wave grid, wave = 64m x 64n

    f32x4 acc[4][4] = {};

    // 24 x 1KB staging units per tile: u<8 -> A (kc=u>>1, half=u&1), u>=8 -> B
    // (v=u-8: kc=v>>2, nq=v&3). 3 units per wave. All sources 1KB contiguous.
    auto stage = [&](int buf, int t) {
#pragma unroll
        for (int i = 0; i < 3; ++i) {
            const int u = wid * 3 + i;          // 0..23
            if (u < 8) {
                const int kc = u >> 1, half = u & 1;
                const int g  = t * 4 + kc;
                const unsigned short* src =
                    Ax + ((size_t)g * NPAD + row0 + half * 64 + lane) * 8;
                unsigned short* dst = &lds[buf][kc * 1024 + half * 512];
                __builtin_amdgcn_global_load_lds(
                    (const __attribute__((address_space(1))) void*)src,
                    (__attribute__((address_space(3))) void*)dst, 16, 0, 0);
            } else {
                const int v = u - 8;
                const int kc = v >> 2, nq = v & 3;
                const int g  = t * 4 + kc;
                const unsigned short* src =
                    Wb + ((size_t)g * ODIM + nq * 64 + lane) * 8;
                unsigned short* dst = &lds[buf][4096 + kc * 2048 + nq * 512];
                __builtin_amdgcn_global_load_lds(
                    (const __attribute__((address_space(1))) void*)src,
                    (__attribute__((address_space(3))) void*)dst, 16, 0, 0);
            }
        }
    };

    stage(0, 0);
    stage(1, 1);
#pragma unroll
    for (int t = 0; t < NTK; ++t) {
        // own 3 loads of tile t done; tile t+1's 3 stay in flight (counted wait)
        if (t < NTK - 1) asm volatile("s_waitcnt vmcnt(3)" ::: "memory");
        else            asm volatile("s_waitcnt vmcnt(0)" ::: "memory");
        __builtin_amdgcn_s_barrier();           // all waves' tile-t loads visible
        __builtin_amdgcn_sched_barrier(0);
        if (t + 2 < NTK) stage((t + 2) % 3, t + 2);  // overwrites buf read at t-1
        const int buf = t % 3;
        bf16x8 af[4], bfr[4];
#pragma unroll
        for (int mi = 0; mi < 4; ++mi)
            af[mi] = *(const bf16x8*)&lds[buf][l4 * 1024 + (wr * 64 + mi * 16 + l15) * 8];
#pragma unroll
        for (int ni = 0; ni < 4; ++ni)
            bfr[ni] = *(const bf16x8*)&lds[buf][4096 + l4 * 2048 + (wc * 64 + ni * 16 + l15) * 8];
#pragma unroll
        for (int mi = 0; mi < 4; ++mi)
#pragma unroll
            for (int ni = 0; ni < 4; ++ni)
                acc[mi][ni] = __builtin_amdgcn_mfma_f32_16x16x32_bf16(
                    af[mi], bfr[ni], acc[mi][ni], 0, 0, 0);
    }

    // epilogue: D layout col=lane&15, row=(lane>>4)*4+r
#pragma unroll
    for (int mi = 0; mi < 4; ++mi) {
        const int row = row0 + wr * 64 + mi * 16 + l4 * 4;
#pragma unroll
        for (int ni = 0; ni < 4; ++ni) {
            const int col = wc * 64 + ni * 16 + l15;
            const float bb = bias[col];
            f32x4 v = acc[mi][ni];
#pragma unroll
            for (int r = 0; r < 4; ++r) {
                const int rr = row + r;
                if (rr < NN) out[(size_t)rr * ODIM + col] = v[r] + bb;
            }
        }
    }
}

// ---------------- launch -------------------------------------------------------
extern "C" void kernel_launch(void* const* d_in, const int* in_sizes, int n_in,
                              void* d_out, int out_size, void* d_ws, size_t ws_size,
                              hipStream_t stream) {
    const float* x      = (const float*)d_in[0];
    const float* Wself  = (const float*)d_in[1];
    const float* bself  = (const float*)d_in[2];
    const float* Wneigh = (const float*)d_in[3];
    const float* bneigh = (const float*)d_in[4];
    const float* Wcoar  = (const float*)d_in[5];
    const float* bcoar  = (const float*)d_in[6];
    const int*   nbr    = (const int*)d_in[7];
    float* out = (float*)d_out;

    // workspace: Ax (77.1 MB, 96 chunks x NPAD x 8 bf16) | X8 (12.8) | Wb | bias ~= 90.3 MB
    unsigned short* Ax   = (unsigned short*)d_ws;
    unsigned char*  X8   = (unsigned char*)(Ax + (size_t)96 * NPAD * 8);
    unsigned short* Wb   = (unsigned short*)(X8 + (size_t)NN * 256);
    float*          bias = (float*)(Wb + (size_t)96 * ODIM * 8);

    k_prep_w<<<768, 256, 0, stream>>>(Wself, bself, Wneigh, bneigh, Wcoar, bcoar, Wb, bias);
    k_convert_x<<<(NN * 32 + 255) / 256, 256, 0, stream>>>(x, Ax, X8);
    k_gather<<<NN / 8, 512, 0, stream>>>(nbr, X8, Ax);
    k_gemm<<<NPAD / 128, 512, 0, stream>>>(Ax, Wb, bias, out);
}

// Round 9
// 98.106 us; speedup vs baseline: 1.6844x; 1.0739x over previous
//
#include <hip/hip_runtime.h>
#include <stdint.h>
#include <stddef.h>

// GraphCoarsenLayer: out = x@W_self + mean(x[nbr[:, :16]])@W_neigh
//                        + mean(x[nbr[:,16:]])@W_coarsen + (b_self+b_neigh+b_coarsen)
// R9: column-sliced gather. fp8 table stored [slice 0..3][node][64B]; per-slice
// working set 3.2MB < 4MB L2/XCD so gather reads become L2 hits (R8 measured only
// 64% L2 hit on the monolithic 12.8MB table, 149MB of ~600cy L3 traffic).
// GEMM/prep unchanged from R8 (BM=128xBN=256, 3-buffer global_load_lds, vmcnt(3)).

#define NN   50000
#define NPAD 50176          // multiple of 128; 392 row-tiles of 128
#define ODIM 256
#define NTK  24             // 768 / 32 K-steps

typedef __bf16 bf16x8 __attribute__((ext_vector_type(8)));
typedef float  f32x4  __attribute__((ext_vector_type(4)));
typedef float  f32x2  __attribute__((ext_vector_type(2)));
typedef unsigned short u16x8 __attribute__((ext_vector_type(8)));
typedef unsigned short u16x4 __attribute__((ext_vector_type(4)));

static __device__ __forceinline__ unsigned short f2b(float f) {
    unsigned u = __builtin_bit_cast(unsigned, f);
    u += 0x7fffu + ((u >> 16) & 1u);          // round-to-nearest-even
    return (unsigned short)(u >> 16);
}

// ---------------- kernel 1: pack weights (K-chunked) + bias sum ----------------
// Wb layout: [g*256 + n]*8 + j  where k = g*8 + j  (g = 0..95)
__global__ void k_prep_w(const float* __restrict__ Wself, const float* __restrict__ bself,
                         const float* __restrict__ Wneigh, const float* __restrict__ bneigh,
                         const float* __restrict__ Wcoar, const float* __restrict__ bcoar,
                         unsigned short* __restrict__ Wb, float* __restrict__ bias) {
    int k = blockIdx.x;      // 0..767
    int n = threadIdx.x;     // 0..255
    const float* W = (k < 256) ? Wself : (k < 512) ? Wneigh : Wcoar;
    int kl = k & 255;
    float v = W[(size_t)kl * ODIM + n];
    int g = k >> 3;
    int j = k & 7;
    Wb[((size_t)g * ODIM + n) * 8 + j] = f2b(v);
    if (k == 0) bias[n] = bself[n] + bneigh[n] + bcoar[n];
}

// ---------------- kernel 2: x (f32) -> Ax chunked g<32 (bf16) + X8s fp8 sliced --
__global__ void k_convert_x(const float* __restrict__ x, unsigned short* __restrict__ Ax,
                            unsigned char* __restrict__ X8s) {
    int p = blockIdx.x * 256 + threadIdx.x;    // one 8-element chunk per thread
    if (p >= NN * 32) return;
    int i  = p >> 5;
    int c8 = p & 31;
    const f32x4* src = (const f32x4*)(x + (size_t)i * 256 + c8 * 8);
    f32x4 v0 = src[0], v1 = src[1];
    u16x8 o;
    o[0] = f2b(v0[0]); o[1] = f2b(v0[1]); o[2] = f2b(v0[2]); o[3] = f2b(v0[3]);
    o[4] = f2b(v1[0]); o[5] = f2b(v1[1]); o[6] = f2b(v1[2]); o[7] = f2b(v1[3]);
    *(u16x8*)(Ax + ((size_t)c8 * NPAD + i) * 8) = o;      // chunked bf16 layout
    unsigned d0 = __builtin_amdgcn_cvt_pk_fp8_f32(v0[0], v0[1], 0, false);
    d0 = (unsigned)__builtin_amdgcn_cvt_pk_fp8_f32(v0[2], v0[3], d0, true);
    unsigned d1 = __builtin_amdgcn_cvt_pk_fp8_f32(v1[0], v1[1], 0, false);
    d1 = (unsigned)__builtin_amdgcn_cvt_pk_fp8_f32(v1[2], v1[3], d1, true);
    uint2 o8; o8.x = d0; o8.y = d1;
    const int s = c8 >> 3, b = c8 & 7;         // column slice 0..3, 8B sub-chunk
    *(uint2*)(X8s + ((size_t)s * NN + i) * 64 + b * 8) = o8;
}

// ---------------- kernel 3: sliced gather-mean -> Ax chunks g 32..95 -----------
// Block = 16 nodes x 1 slice (64 cols). 16 lanes per node, 4B/lane. Per-slice
// table (3.2MB) is L2-resident. Grid (3125, 4): slice on y -> time-windowed.
__global__ __launch_bounds__(256) void k_gather(const int* __restrict__ nbr,
                                                const unsigned char* __restrict__ X8s,
                                                unsigned short* __restrict__ Ax) {
    __shared__ int nbl[512];                     // 16 nodes x 32 neighbor ids
    __shared__ unsigned short aggl[16][136];     // [node][s 0..63 | u 64..127 | pad]
    const int tid   = threadIdx.x;
    const int node0 = blockIdx.x * 16;           // 3125 * 16 = 50000 exactly
    const int s     = blockIdx.y;                // slice 0..3
    nbl[tid]       = nbr[(size_t)node0 * 32 + tid];
    nbl[tid + 256] = nbr[(size_t)node0 * 32 + 256 + tid];
    __syncthreads();

    const int wid = tid >> 6, lane = tid & 63;
    const int nl  = wid * 4 + (lane >> 4);       // local node 0..15
    const int col = lane & 15;                   // 4B column group in slice
    const unsigned char* base = X8s + (size_t)s * NN * 64 + col * 4;
    float s0 = 0, s1 = 0, s2 = 0, s3 = 0, u0 = 0, u1 = 0, u2 = 0, u3 = 0;
#pragma unroll
    for (int j = 0; j < 32; ++j) {
        const int idx = nbl[nl * 32 + j];
        unsigned d = *(const unsigned*)(base + (size_t)idx * 64);
        f32x2 lo = __builtin_amdgcn_cvt_pk_f32_fp8(d, false);
        f32x2 hi = __builtin_amdgcn_cvt_pk_f32_fp8(d, true);
        if (j < 16) { s0 += lo[0]; s1 += lo[1]; s2 += hi[0]; s3 += hi[1]; }
        else        { u0 += lo[0]; u1 += lo[1]; u2 += hi[0]; u3 += hi[1]; }
    }
    const float rc = 1.0f / 16.0f;
    u16x4 os = { f2b(s0 * rc), f2b(s1 * rc), f2b(s2 * rc), f2b(s3 * rc) };
    u16x4 ou = { f2b(u0 * rc), f2b(u1 * rc), f2b(u2 * rc), f2b(u3 * rc) };
    *(u16x4*)&aggl[nl][col * 4]      = os;
    *(u16x4*)&aggl[nl][64 + col * 4] = ou;
    __syncthreads();

    // write-out: thread tau -> (gch = tau>>4, row = tau&15); 16 consecutive threads
    // write 16 consecutive rows of one g-chunk = 256B contiguous in Ax.
    const int gch = tid >> 4, row = tid & 15;
    u16x8 v = *(const u16x8*)&aggl[row][gch * 8];
    const int g = (gch < 8) ? (32 + s * 8 + gch) : (64 + s * 8 + (gch - 8));
    *(u16x8*)(Ax + ((size_t)g * NPAD + node0 + row) * 8) = v;
}

// ---------------- kernel 4: GEMM  out[N,256] = A[N,768] @ Wb + bias ------------
// BM=128, BN=256 (A read once), BK=32. 512 threads = 8 waves (2x4), wave 64x64.
// 3-buffer LDS, counted vmcnt(3), ONE barrier per K-step.  (unchanged from R8)
__global__ __launch_bounds__(512, 4) void k_gemm(const unsigned short* __restrict__ Ax,
                                                 const unsigned short* __restrict__ Wb,
                                                 const float* __restrict__ bias,
                                                 float* __restrict__ out) {
    __shared__ __align__(16) unsigned short lds[3][12288];  // [buf][A 4096 | B 8192] u16
    const int tid  = threadIdx.x;
    const int wid  = tid >> 6;
    const int lane = tid & 63;
    const int l15 = lane & 15, l4 = lane >> 4;
    const int row0 = blockIdx.x * 128;
    const int wr = wid >> 2, wc = wid & 3;      // 2x4 wave grid, wave = 64m x 64n

    f32x4 acc[4][4] = {};

    auto stage = [&](int buf, int t) {
#pragma unroll
        for (int i = 0; i < 3; ++i) {
            const int u = wid * 3 + i;          // 0..23
            if (u < 8) {
                const int kc = u >> 1, half = u & 1;
                const int g  = t * 4 + kc;
                const unsigned short* src =
                    Ax + ((size_t)g * NPAD + row0 + half * 64 + lane) * 8;
                unsigned short* dst = &lds[buf][kc * 1024 + half * 512];
                __builtin_amdgcn_global_load_lds(
                    (const __attribute__((address_space(1))) void*)src,
                    (__attribute__((address_space(3))) void*)dst, 16, 0, 0);
            } else {
                const int v = u - 8;
                const int kc = v >> 2, nq = v & 3;
                const int g  = t * 4 + kc;
                const unsigned short* src =
                    Wb + ((size_t)g * ODIM + nq * 64 + lane) * 8;
                unsigned short* dst = &lds[buf][4096 + kc * 2048 + nq * 512];
                __builtin_amdgcn_global_load_lds(
                    (const __attribute__((address_space(1))) void*)src,
                    (__attribute__((address_space(3))) void*)dst, 16, 0, 0);
            }
        }
    };

    stage(0, 0);
    stage(1, 1);
#pragma unroll
    for (int t = 0; t < NTK; ++t) {
        if (t < NTK - 1) asm volatile("s_waitcnt vmcnt(3)" ::: "memory");
        else            asm volatile("s_waitcnt vmcnt(0)" ::: "memory");
        __builtin_amdgcn_s_barrier();           // all waves' tile-t loads visible
        __builtin_amdgcn_sched_barrier(0);
        if (t + 2 < NTK) stage((t + 2) % 3, t + 2);  // overwrites buf read at t-1
        const int buf = t % 3;
        bf16x8 af[4], bfr[4];
#pragma unroll
        for (int mi = 0; mi < 4; ++mi)
            af[mi] = *(const bf16x8*)&lds[buf][l4 * 1024 + (wr * 64 + mi * 16 + l15) * 8];
#pragma unroll
        for (int ni = 0; ni < 4; ++ni)
            bfr[ni] = *(const bf16x8*)&lds[buf][4096 + l4 * 2048 + (wc * 64 + ni * 16 + l15) * 8];
#pragma unroll
        for (int mi = 0; mi < 4; ++mi)
#pragma unroll
            for (int ni = 0; ni < 4; ++ni)
                acc[mi][ni] = __builtin_amdgcn_mfma_f32_16x16x32_bf16(
                    af[mi], bfr[ni], acc[mi][ni], 0, 0, 0);
    }

    // epilogue: D layout col=lane&15, row=(lane>>4)*4+r
#pragma unroll
    for (int mi = 0; mi < 4; ++mi) {
        const int row = row0 + wr * 64 + mi * 16 + l4 * 4;
#pragma unroll
        for (int ni = 0; ni < 4; ++ni) {
            const int col = wc * 64 + ni * 16 + l15;
            const float bb = bias[col];
            f32x4 v = acc[mi][ni];
#pragma unroll
            for (int r = 0; r < 4; ++r) {
                const int rr = row + r;
                if (rr < NN) out[(size_t)rr * ODIM + col] = v[r] + bb;
            }
        }
    }
}

// ---------------- launch -------------------------------------------------------
extern "C" void kernel_launch(void* const* d_in, const int* in_sizes, int n_in,
                              void* d_out, int out_size, void* d_ws, size_t ws_size,
                              hipStream_t stream) {
    const float* x      = (const float*)d_in[0];
    const float* Wself  = (const float*)d_in[1];
    const float* bself  = (const float*)d_in[2];
    const float* Wneigh = (const float*)d_in[3];
    const float* bneigh = (const float*)d_in[4];
    const float* Wcoar  = (const float*)d_in[5];
    const float* bcoar  = (const float*)d_in[6];
    const int*   nbr    = (const int*)d_in[7];
    float* out = (float*)d_out;

    // workspace: Ax (77.1 MB, 96 chunks x NPAD x 8 bf16) | X8s (12.8) | Wb | bias ~= 90.3 MB
    unsigned short* Ax   = (unsigned short*)d_ws;
    unsigned char*  X8s  = (unsigned char*)(Ax + (size_t)96 * NPAD * 8);
    unsigned short* Wb   = (unsigned short*)(X8s + (size_t)4 * NN * 64);
    float*          bias = (float*)(Wb + (size_t)96 * ODIM * 8);

    k_prep_w<<<768, 256, 0, stream>>>(Wself, bself, Wneigh, bneigh, Wcoar, bcoar, Wb, bias);
    k_convert_x<<<(NN * 32 + 255) / 256, 256, 0, stream>>>(x, Ax, X8s);
    k_gather<<<dim3(3125, 4), 256, 0, stream>>>(nbr, X8s, Ax);
    k_gemm<<<NPAD / 128, 512, 0, stream>>>(Ax, Wb, bias, out);
}